// Round 7
// baseline (5076.160 us; speedup 1.0000x reference)
//
#include <hip/hip_runtime.h>
#include <hip/hip_bf16.h>
#include <math.h>

// Problem constants (MiniTrajectoryPredictor)
#define BB 32
#define TT 24
#define OO 128
#define HH 512
#define CTXD 256
#define HOR 48
#define NN (BB*OO)        // 4096
#define G3 (3*HH)         // 1536
#define KS2 16            // k-steps of 32 (K = 512 exactly; x/bias in epilogue)
#define TILE_U16 (KS2*512)  // 8192 u16 per 16-row fragment tile (power of 2)

typedef unsigned short ushortt;
typedef __attribute__((ext_vector_type(8))) short bf16x8;
typedef __attribute__((ext_vector_type(4))) float f32x4;

// ---- bf16 split helpers ----
__device__ __forceinline__ ushortt f2bf(float x) {
    union { float f; unsigned u; } v; v.f = x;
    unsigned r = v.u + 0x7FFF + ((v.u >> 16) & 1);
    return (ushortt)(r >> 16);
}
__device__ __forceinline__ float bf2f(ushortt b) {
    union { unsigned u; float f; } v; v.u = ((unsigned)b) << 16;
    return v.f;
}
__device__ __forceinline__ void splitbf(float x, ushortt& hi, ushortt& lo) {
    hi = f2bf(x);
    lo = f2bf(x - bf2f(hi));
}
__device__ __forceinline__ float sigm(float x) { return 1.f / (1.f + __expf(-x)); }
__device__ __forceinline__ float tanh_fast(float x) {
    float xc = fminf(fmaxf(x, -10.f), 10.f);
    float e = __expf(2.f * xc);
    return (e - 1.f) / (e + 1.f);
}

// 16-block group barrier (all members on one XCD via mb%8 placement).
// Monotonic target counter; release on arrive, acquire after pass.
__device__ __forceinline__ void group_barrier(unsigned* cnt, unsigned target) {
    __syncthreads();   // drains each wave's vmem (compiler emits vmcnt(0) before s_barrier)
    if (threadIdx.x == 0) {
        __hip_atomic_fetch_add(cnt, 1u, __ATOMIC_RELEASE, __HIP_MEMORY_SCOPE_AGENT);
        while (__hip_atomic_load(cnt, __ATOMIC_RELAXED, __HIP_MEMORY_SCOPE_AGENT) < target)
            __builtin_amdgcn_s_sleep(2);
        (void)__hip_atomic_load(cnt, __ATOMIC_ACQUIRE, __HIP_MEMORY_SCOPE_AGENT);
    }
    __syncthreads();
}

// Fragment layout (verified R2+): element (row r, k) of a 16-row tile:
// lane = ((k%32)>>3)*16 + (r%16), slot = k%8; buffer [tile][ks][lane][slot] u16.
// C/D: col = lane&15, row = (lane>>4)*4 + reg.

#define MLOADA(Ad, ksv) do { const unsigned ko = (unsigned)(ksv) * 512; \
  _Pragma("unroll") for (int m_ = 0; m_ < 2; m_++) { \
    Ad[m_*2+0] = *reinterpret_cast<const bf16x8*>(RAh + ao[m_] + ko); \
    Ad[m_*2+1] = *reinterpret_cast<const bf16x8*>(RAl + ao[m_] + ko); \
  } } while(0)
#define MLOADB(Bd, ksv) do { const unsigned ko = (unsigned)(ksv) * 512; \
  _Pragma("unroll") for (int i_ = 0; i_ < 6; i_++) { \
    Bd[i_*2+0] = *reinterpret_cast<const bf16x8*>(Bh + bo[i_] + ko); \
    Bd[i_*2+1] = *reinterpret_cast<const bf16x8*>(Bl + bo[i_] + ko); \
  } } while(0)
#define MMFMA(Av, Bv) do { \
  _Pragma("unroll") for (int m_ = 0; m_ < 2; m_++) \
  _Pragma("unroll") for (int i_ = 0; i_ < 6; i_++) \
    acc[m_][i_] = __builtin_amdgcn_mfma_f32_16x16x32_bf16(Av[m_*2+0], Bv[i_*2+0], acc[m_][i_], 0,0,0); \
  _Pragma("unroll") for (int m_ = 0; m_ < 2; m_++) \
  _Pragma("unroll") for (int i_ = 0; i_ < 6; i_++) \
    acc[m_][i_] = __builtin_amdgcn_mfma_f32_16x16x32_bf16(Av[m_*2+0], Bv[i_*2+1], acc[m_][i_], 0,0,0); \
  _Pragma("unroll") for (int m_ = 0; m_ < 2; m_++) \
  _Pragma("unroll") for (int i_ = 0; i_ < 6; i_++) \
    acc[m_][i_] = __builtin_amdgcn_mfma_f32_16x16x32_bf16(Av[m_*2+1], Bv[i_*2+0], acc[m_][i_], 0,0,0); \
  } while(0)

#define HLOADA(Ad, ksv) do { const unsigned ko = (unsigned)(ksv) * 512; \
  _Pragma("unroll") for (int m_ = 0; m_ < 2; m_++) { \
    Ad[m_*2+0] = *reinterpret_cast<const bf16x8*>(WAh + ao[m_] + ko); \
    Ad[m_*2+1] = *reinterpret_cast<const bf16x8*>(WAl + ao[m_] + ko); \
  } } while(0)
#define HLOADB(Bd, ksv) do { const unsigned ko = (unsigned)(ksv) * 512; \
  _Pragma("unroll") for (int n_ = 0; n_ < 2; n_++) { \
    Bd[n_*2+0] = *reinterpret_cast<const bf16x8*>(W1H + bo1[n_] + ko); \
    Bd[n_*2+1] = *reinterpret_cast<const bf16x8*>(W1L + bo1[n_] + ko); \
  } } while(0)
#define HMFMA(Av, Bv) do { \
  _Pragma("unroll") for (int m_ = 0; m_ < 2; m_++) \
  _Pragma("unroll") for (int n_ = 0; n_ < 2; n_++) { \
    hacc[m_][n_] = __builtin_amdgcn_mfma_f32_16x16x32_bf16(Av[m_*2+0], Bv[n_*2+0], hacc[m_][n_], 0,0,0); \
    hacc[m_][n_] = __builtin_amdgcn_mfma_f32_16x16x32_bf16(Av[m_*2+0], Bv[n_*2+1], hacc[m_][n_], 0,0,0); \
    hacc[m_][n_] = __builtin_amdgcn_mfma_f32_16x16x32_bf16(Av[m_*2+1], Bv[n_*2+0], hacc[m_][n_], 0,0,0); \
  } } while(0)

// ================= persistent kernel: all 72 steps, 2 blocks/CU =================
__global__ __launch_bounds__(256, 2) void main_kernel(
    ushortt* Ah0, ushortt* Al0, ushortt* Ah1, ushortt* Al1,
    const ushortt* __restrict__ WheH, const ushortt* __restrict__ WheL,
    const ushortt* __restrict__ WhdH, const ushortt* __restrict__ WhdL,
    const ushortt* __restrict__ W1H,  const ushortt* __restrict__ W1L,
    const float* __restrict__ Ue, const float* __restrict__ ce,
    const float* __restrict__ Ud, const float* __restrict__ cd,
    const float* __restrict__ bhe, const float* __restrict__ bhd,
    const float* __restrict__ traj, const float* __restrict__ ctx,
    const float* __restrict__ b1v, const float* __restrict__ W2,
    const float* __restrict__ b2v, float* __restrict__ dpart,
    unsigned* bar, float* __restrict__ out)
{
    __shared__ float hbuf[128 * 36];     // epilogue repack staging
    __shared__ float sstate[128 * 2];    // decoder state (redundant per group)
    const int mb = blockIdx.x & 31;      // LOW bits -> XCD = mb%8; group = same mb
    const int jb = blockIdx.x >> 5;      // 0..15
    const int w = threadIdx.x >> 6, lane = threadIdx.x & 63;
    const int quad = lane >> 4, l15 = lane & 15;
    const int mtg = mb * 8 + w * 2;      // wave's 2 global m-tiles
    const int jlo = jb * 32;
    unsigned* grpcnt = bar + mb * 16;    // padded counter per group
    unsigned tgt = 0;

    ushortt* bh_[2] = {Ah0, Ah1};
    ushortt* bl_[2] = {Al0, Al1};

    unsigned ao[2], bo[6], bo1[2];
#pragma unroll
    for (int mt = 0; mt < 2; mt++) ao[mt] = (unsigned)(mtg + mt) * TILE_U16 + lane * 8;
#pragma unroll
    for (int g = 0; g < 3; g++)
#pragma unroll
        for (int jt = 0; jt < 2; jt++)
            bo[g*2+jt] = (unsigned)(g*32 + jb*2 + jt) * TILE_U16 + lane * 8;
#pragma unroll
    for (int nt = 0; nt < 2; nt++) bo1[nt] = (unsigned)(jb*2 + nt) * TILE_U16 + lane * 8;

    // head constants (fixed all steps)
    float b1r[2], w2a[2], w2b[2];
#pragma unroll
    for (int nt = 0; nt < 2; nt++) {
        int col = jlo + nt*16 + l15;
        b1r[nt] = b1v[col]; w2a[nt] = W2[col]; w2b[nt] = W2[HH + col];
    }
    const float b20 = b2v[0], b21 = b2v[1];

    // per-phase GRU epilogue constants
    float Ur0[2],Ur1[2],Uz0[2],Uz1[2],Un0[2],Un1[2],Crr[2],Czz[2],bhn[2],cinn[2];

#pragma unroll 1
    for (int s = 0; s < TT + HOR; s++) {
        const bool enc = s < TT;
        if (s == 0 || s == TT) {
            const float* U  = enc ? Ue : Ud;
            const float* ci = enc ? ce : cd;
            const float* bh = enc ? bhe : bhd;
#pragma unroll
            for (int jt = 0; jt < 2; jt++) {
                int j = jlo + jt*16 + l15;
                Ur0[jt] = U[j*2];            Ur1[jt] = U[j*2+1];
                Uz0[jt] = U[(512+j)*2];      Uz1[jt] = U[(512+j)*2+1];
                Un0[jt] = U[(1024+j)*2];     Un1[jt] = U[(1024+j)*2+1];
                Crr[jt] = ci[j] + bh[j];
                Czz[jt] = ci[512+j] + bh[512+j];
                cinn[jt] = ci[1024+j];       bhn[jt] = bh[1024+j];
            }
            if (!enc) {
                if (threadIdx.x < 128) {
                    int lrow = threadIdx.x;
                    const float* sp = traj + (((size_t)mb * TT + 23) * OO + lrow) * 2;
                    sstate[lrow*2] = sp[0]; sstate[lrow*2+1] = sp[1];
                }
                __syncthreads();
            }
        }
        const ushortt* RAh = bh_[s & 1];
        const ushortt* RAl = bl_[s & 1];
        ushortt* WAh = bh_[(s + 1) & 1];
        ushortt* WAl = bl_[(s + 1) & 1];
        const ushortt* Bh = enc ? WheH : WhdH;
        const ushortt* Bl = enc ? WheL : WhdL;

        f32x4 acc[2][6];
#pragma unroll
        for (int a = 0; a < 2; a++)
#pragma unroll
            for (int b = 0; b < 6; b++) acc[a][b] = (f32x4){0.f,0.f,0.f,0.f};

        if (s > 0) {
            bf16x8 aC[4], bC[12], aN[4], bN[12];
            MLOADA(aC, 0); MLOADB(bC, 0);
#pragma unroll 1
            for (int ks = 0; ks < 14; ks += 2) {
                MLOADA(aN, ks+1); MLOADB(bN, ks+1);
                MMFMA(aC, bC);
                MLOADA(aC, ks+2); MLOADB(bC, ks+2);
                MMFMA(aN, bN);
            }
            MLOADA(aN, 15); MLOADB(bN, 15);
            MMFMA(aC, bC);   // ks = 14
            MMFMA(aN, bN);   // ks = 15
        }

        // ---- x values per (mt, reg) row ----
        float x0v[2][4], x1v[2][4];
#pragma unroll
        for (int mt = 0; mt < 2; mt++)
#pragma unroll
            for (int reg = 0; reg < 4; reg++) {
                int lrow = (w*2 + mt) * 16 + quad * 4 + reg;
                if (enc) {
                    const float* p = traj + (((size_t)mb * TT + s) * OO + lrow) * 2;
                    x0v[mt][reg] = p[0]; x1v[mt][reg] = p[1];
                } else {
                    x0v[mt][reg] = sstate[lrow*2]; x1v[mt][reg] = sstate[lrow*2+1];
                }
            }

        // ---- GRU epilogue ----
#pragma unroll
        for (int mt = 0; mt < 2; mt++)
#pragma unroll
            for (int jt = 0; jt < 2; jt++) {
                int qk = jt*2 + (l15 >> 3), slot = l15 & 7;
#pragma unroll
                for (int reg = 0; reg < 4; reg++) {
                    float x0 = x0v[mt][reg], x1 = x1v[mt][reg];
                    float pr = acc[mt][0+jt][reg] + fmaf(x1, Ur1[jt], fmaf(x0, Ur0[jt], Crr[jt]));
                    float pz = acc[mt][2+jt][reg] + fmaf(x1, Uz1[jt], fmaf(x0, Uz0[jt], Czz[jt]));
                    float hn = acc[mt][4+jt][reg] + bhn[jt];
                    float inn = fmaf(x1, Un1[jt], fmaf(x0, Un0[jt], cinn[jt]));
                    float hold = 0.f;
                    if (s > 0) {
                        unsigned pos = (unsigned)(mtg + mt) * TILE_U16 + (unsigned)jb * 512
                                     + (unsigned)(qk*16 + quad*4 + reg) * 8 + slot;
                        hold = bf2f(RAh[pos]) + bf2f(RAl[pos]);
                    }
                    float rg = sigm(pr), zg = sigm(pz);
                    float nn = tanh_fast(inn + rg * hn);
                    float h = (1.f - zg) * nn + zg * hold;
                    if (enc && s == TT - 1)
                        h += ctx[(size_t)mb * HH + jlo + jt*16 + l15];
                    hbuf[(w*32 + mt*16 + quad*4 + reg) * 36 + jt*16 + l15] = h;
                }
            }
        __syncthreads();
        // repack LDS tile -> A-frags slice ks == jb of write buffer
#pragma unroll
        for (int rr = 0; rr < 2; rr++) {
            int fr = threadIdx.x + 256 * rr;       // 0..511
            int mt8 = fr >> 6, fl = fr & 63;
            int qk = fl >> 4, rloc = mt8 * 16 + (fl & 15);
            const float4 v0 = *reinterpret_cast<const float4*>(&hbuf[rloc * 36 + qk * 8]);
            const float4 v1 = *reinterpret_cast<const float4*>(&hbuf[rloc * 36 + qk * 8 + 4]);
            float src[8] = {v0.x, v0.y, v0.z, v0.w, v1.x, v1.y, v1.z, v1.w};
            bf16x8 hv, lv;
#pragma unroll
            for (int q = 0; q < 8; q++) {
                ushortt hi, lo; splitbf(src[q], hi, lo);
                hv[q] = (short)hi; lv[q] = (short)lo;
            }
            unsigned base = (unsigned)(mb*8 + mt8) * TILE_U16 + (unsigned)jb * 512 + fl * 8;
            *reinterpret_cast<bf16x8*>(WAh + base) = hv;
            *reinterpret_cast<bf16x8*>(WAl + base) = lv;
        }
        __syncthreads();   // hbuf reuse safety (next iteration writes hbuf)

        // B1: h_{s+1} frags complete for this group
        tgt += 16;
        group_barrier(grpcnt, tgt);

        if (!enc) {
            // ---- head: this block does W1 cols [jb*32, jb*32+32) for its 128 rows ----
            f32x4 hacc[2][2];
#pragma unroll
            for (int a = 0; a < 2; a++)
#pragma unroll
                for (int b = 0; b < 2; b++) hacc[a][b] = (f32x4){0.f,0.f,0.f,0.f};
            {
                bf16x8 aC[4], bC[4], aN[4], bN[4];
                HLOADA(aC, 0); HLOADB(bC, 0);
#pragma unroll 1
                for (int ks = 0; ks < 14; ks += 2) {
                    HLOADA(aN, ks+1); HLOADB(bN, ks+1);
                    HMFMA(aC, bC);
                    HLOADA(aC, ks+2); HLOADB(bC, ks+2);
                    HMFMA(aN, bN);
                }
                HLOADA(aN, 15); HLOADB(bN, 15);
                HMFMA(aC, bC);
                HMFMA(aN, bN);
            }
            float p0[2][4], p1[2][4];
#pragma unroll
            for (int mt = 0; mt < 2; mt++)
#pragma unroll
                for (int reg = 0; reg < 4; reg++) { p0[mt][reg] = 0.f; p1[mt][reg] = 0.f; }
#pragma unroll
            for (int mt = 0; mt < 2; mt++)
#pragma unroll
                for (int nt = 0; nt < 2; nt++)
#pragma unroll
                    for (int reg = 0; reg < 4; reg++) {
                        float v = hacc[mt][nt][reg] + b1r[nt];
                        v = 0.5f * v * (1.0f + erff(v * 0.70710678118654752440f));
                        p0[mt][reg] = fmaf(v, w2a[nt], p0[mt][reg]);
                        p1[mt][reg] = fmaf(v, w2b[nt], p1[mt][reg]);
                    }
#pragma unroll
            for (int m = 1; m < 16; m <<= 1)
#pragma unroll
                for (int mt = 0; mt < 2; mt++)
#pragma unroll
                    for (int reg = 0; reg < 4; reg++) {
                        p0[mt][reg] += __shfl_xor(p0[mt][reg], m, 64);
                        p1[mt][reg] += __shfl_xor(p1[mt][reg], m, 64);
                    }
            if (l15 == 0) {
#pragma unroll
                for (int mt = 0; mt < 2; mt++)
#pragma unroll
                    for (int reg = 0; reg < 4; reg++) {
                        int lrow = (w*2 + mt) * 16 + quad * 4 + reg;
                        float* dp = dpart + ((size_t)(mb*16 + jb) * 128 + lrow) * 2;
                        dp[0] = p0[mt][reg]; dp[1] = p1[mt][reg];
                    }
            }
            // B2: all partials visible
            tgt += 16;
            group_barrier(grpcnt, tgt);
            // ---- finalize: reduce partials, update state (LDS), write out ----
            if (threadIdx.x < 128) {
                int lrow = threadIdx.x;
                float d0 = 0.f, d1 = 0.f;
#pragma unroll
                for (int j2 = 0; j2 < 16; j2++) {
                    const float* dp = dpart + ((size_t)(mb*16 + j2) * 128 + lrow) * 2;
                    d0 += dp[0]; d1 += dp[1];
                }
                d0 += b20; d1 += b21;
                d0 = 2.0f * tanhf(d0 * 0.5f);
                d1 = 2.0f * tanhf(d1 * 0.5f);
                float s0 = sstate[lrow*2] + d0;
                s0 = fminf(fmaxf(s0, -90.f), 90.f);
                float s1 = sstate[lrow*2+1] + d1;
                float rrm = fmodf(s1, 360.f);
                if (rrm < 0.f) rrm += 360.f;
                sstate[lrow*2] = s0; sstate[lrow*2+1] = rrm;
                if (jb == 0) {
                    float* op = out + (((size_t)mb * HOR + (s - TT)) * OO + lrow) * 2;
                    op[0] = s0; op[1] = rrm;
                }
            }
            __syncthreads();   // sstate ready for next step's epilogue
        }
    }
}

// ================= single prep kernel: packs + fuse + ctx + barrier zero =================
__device__ __forceinline__ void pack16(const float* __restrict__ W,
                                       ushortt* __restrict__ Fh, ushortt* __restrict__ Fl,
                                       int item) {
    int n = item >> 6, rem = item & 63;
    int ks = rem >> 2, quadk = rem & 3;
    int nt = n >> 4, l15 = n & 15;
    ushortt hv[8], lv[8];
#pragma unroll
    for (int q = 0; q < 8; q++) {
        float v = W[(size_t)n * 512 + ks*32 + quadk*8 + q];
        ushortt hi, lo; splitbf(v, hi, lo);
        hv[q] = hi; lv[q] = lo;
    }
    size_t pos = ((size_t)nt * TILE_U16) + (size_t)ks * 512 + (quadk*16 + l15) * 8;
#pragma unroll
    for (int q = 0; q < 8; q++) { Fh[pos + q] = hv[q]; Fl[pos + q] = lv[q]; }
}

__global__ __launch_bounds__(256) void prep_kernel(
    const float* __restrict__ Wh_enc, const float* __restrict__ Wh_cell,
    const float* __restrict__ W1,
    const float* __restrict__ Wi_enc, const float* __restrict__ bi_enc,
    const float* __restrict__ Wi_cell, const float* __restrict__ bi_cell,
    const float* __restrict__ W_emb, const float* __restrict__ b_emb,
    const float* __restrict__ z, const float* __restrict__ Wc, const float* __restrict__ bc,
    ushortt* __restrict__ WheH, ushortt* __restrict__ WheL,
    ushortt* __restrict__ WhdH, ushortt* __restrict__ WhdL,
    ushortt* __restrict__ W1H, ushortt* __restrict__ W1L,
    float* __restrict__ Ue, float* __restrict__ ce,
    float* __restrict__ Ud, float* __restrict__ cd,
    float* __restrict__ ctx, unsigned* __restrict__ bar)
{
    int b = blockIdx.x;
    if (b < 384) {
        pack16(Wh_enc, WheH, WheL, b * 256 + threadIdx.x);
    } else if (b < 768) {
        pack16(Wh_cell, WhdH, WhdL, (b - 384) * 256 + threadIdx.x);
    } else if (b < 896) {
        pack16(W1, W1H, W1L, (b - 768) * 256 + threadIdx.x);
    } else if (b < 1664) {
        // fuse: wave per output j (U = Wi*W_emb, c = Wi*b_emb + bi)
        int w = threadIdx.x >> 6, lane = threadIdx.x & 63;
        int gidx = (b - 896) * 4 + w;           // 0..3071
        int which = gidx >= G3;
        int j = gidx - which * G3;
        const float* Wi = which ? Wi_cell : Wi_enc;
        const float* bi = which ? bi_cell : bi_enc;
        float u0 = 0.f, u1 = 0.f, cc = 0.f;
#pragma unroll
        for (int i = 0; i < 8; i++) {
            int k = i * 64 + lane;
            float wv = Wi[(size_t)j * HH + k];
            u0 = fmaf(wv, W_emb[2*k],   u0);
            u1 = fmaf(wv, W_emb[2*k+1], u1);
            cc = fmaf(wv, b_emb[k],     cc);
        }
#pragma unroll
        for (int m = 1; m < 64; m <<= 1) {
            u0 += __shfl_xor(u0, m, 64);
            u1 += __shfl_xor(u1, m, 64);
            cc += __shfl_xor(cc, m, 64);
        }
        if (lane == 0) {
            float* Uo = which ? Ud : Ue;
            float* cv = which ? cd : ce;
            Uo[j*2] = u0; Uo[j*2+1] = u1; cv[j] = cc + bi[j];
        }
    } else if (b < 1728) {
        // ctx = z @ Wc^T + bc   (32 x 512)
        int idx = (b - 1664) * 256 + threadIdx.x;
        int bb = idx >> 9, j = idx & 511;
        float acc = bc[j];
        const float4* zp = (const float4*)(z + (size_t)bb * CTXD);
        const float4* wp = (const float4*)(Wc + (size_t)j * CTXD);
#pragma unroll 4
        for (int k = 0; k < CTXD / 4; k++) {
            float4 a = zp[k], ww = wp[k];
            acc = fmaf(a.x, ww.x, fmaf(a.y, ww.y, fmaf(a.z, ww.z, fmaf(a.w, ww.w, acc))));
        }
        ctx[idx] = acc;
    } else {
        bar[threadIdx.x] = 0u;
        bar[threadIdx.x + 256] = 0u;
    }
}

extern "C" void kernel_launch(void* const* d_in, const int* in_sizes, int n_in,
                              void* d_out, int out_size, void* d_ws, size_t ws_size,
                              hipStream_t stream) {
    const float* z_ctx   = (const float*)d_in[0];
    const float* traj    = (const float*)d_in[1];
    const float* W_emb   = (const float*)d_in[2];
    const float* b_emb   = (const float*)d_in[3];
    const float* W_ctx   = (const float*)d_in[4];
    const float* b_ctx   = (const float*)d_in[5];
    const float* Wi_enc  = (const float*)d_in[6];
    const float* Wh_enc  = (const float*)d_in[7];
    const float* bi_enc  = (const float*)d_in[8];
    const float* bh_enc  = (const float*)d_in[9];
    const float* Wi_cell = (const float*)d_in[10];
    const float* Wh_cell = (const float*)d_in[11];
    const float* bi_cell = (const float*)d_in[12];
    const float* bh_cell = (const float*)d_in[13];
    const float* W1      = (const float*)d_in[14];
    const float* b1      = (const float*)d_in[15];
    const float* W2      = (const float*)d_in[16];
    const float* b2      = (const float*)d_in[17];
    float* out = (float*)d_out;

    char* ws = (char*)d_ws;
    size_t off = 0;
    auto alloc = [&](size_t bytes) { void* p = ws + off; off += (bytes + 255) & ~(size_t)255; return p; };
    const size_t hfrag  = (size_t)256 * TILE_U16 * 2;   // 4 MB per h buffer
    const size_t wfrag  = (size_t)96  * TILE_U16 * 2;   // Wh (96 tiles)
    const size_t w1frag = (size_t)32  * TILE_U16 * 2;   // W1 (32 tiles)
    ushortt* Ah0 = (ushortt*)alloc(hfrag);
    ushortt* Al0 = (ushortt*)alloc(hfrag);
    ushortt* Ah1 = (ushortt*)alloc(hfrag);
    ushortt* Al1 = (ushortt*)alloc(hfrag);
    ushortt* WheH = (ushortt*)alloc(wfrag);
    ushortt* WheL = (ushortt*)alloc(wfrag);
    ushortt* WhdH = (ushortt*)alloc(wfrag);
    ushortt* WhdL = (ushortt*)alloc(wfrag);
    ushortt* W1H  = (ushortt*)alloc(w1frag);
    ushortt* W1L  = (ushortt*)alloc(w1frag);
    float*   Ue   = (float*)alloc((size_t)G3 * 2 * 4);
    float*   ce   = (float*)alloc((size_t)G3 * 4);
    float*   Ud   = (float*)alloc((size_t)G3 * 2 * 4);
    float*   cd   = (float*)alloc((size_t)G3 * 4);
    float*   ctxb = (float*)alloc((size_t)BB * HH * 4);
    float*   dpart = (float*)alloc((size_t)32 * 16 * 128 * 2 * 4);  // 512 KB
    unsigned* bar  = (unsigned*)alloc(512 * 4);

    prep_kernel<<<1729, 256, 0, stream>>>(Wh_enc, Wh_cell, W1,
                                          Wi_enc, bi_enc, Wi_cell, bi_cell,
                                          W_emb, b_emb, z_ctx, W_ctx, b_ctx,
                                          WheH, WheL, WhdH, WhdL, W1H, W1L,
                                          Ue, ce, Ud, cd, ctxb, bar);

    main_kernel<<<512, 256, 0, stream>>>(Ah0, Al0, Ah1, Al1,
                                         WheH, WheL, WhdH, WhdL, W1H, W1L,
                                         Ue, ce, Ud, cd, bh_enc, bh_cell,
                                         traj, ctxb, b1, W2, b2,
                                         dpart, bar, out);
}

// Round 8
// 3497.897 us; speedup vs baseline: 1.4512x; 1.4512x over previous
//
#include <hip/hip_runtime.h>
#include <hip/hip_bf16.h>
#include <math.h>

// Problem constants (MiniTrajectoryPredictor)
#define BB 32
#define TT 24
#define OO 128
#define HH 512
#define CTXD 256
#define HOR 48
#define NN (BB*OO)        // 4096
#define G3 (3*HH)         // 1536
#define KS2 16            // k-steps of 32 (K = 512 exactly; x/bias in epilogue)
#define TILE_U16 (KS2*512)  // 8192 u16 per 16-row fragment tile (power of 2)

typedef unsigned short ushortt;
typedef __attribute__((ext_vector_type(8))) short bf16x8;
typedef __attribute__((ext_vector_type(4))) float f32x4;

// ---- bf16 split helpers ----
__device__ __forceinline__ ushortt f2bf(float x) {
    union { float f; unsigned u; } v; v.f = x;
    unsigned r = v.u + 0x7FFF + ((v.u >> 16) & 1);
    return (ushortt)(r >> 16);
}
__device__ __forceinline__ float bf2f(ushortt b) {
    union { unsigned u; float f; } v; v.u = ((unsigned)b) << 16;
    return v.f;
}
__device__ __forceinline__ void splitbf(float x, ushortt& hi, ushortt& lo) {
    hi = f2bf(x);
    lo = f2bf(x - bf2f(hi));
}
__device__ __forceinline__ float sigm(float x) { return 1.f / (1.f + __expf(-x)); }
__device__ __forceinline__ float tanh_fast(float x) {
    float xc = fminf(fmaxf(x, -10.f), 10.f);
    float e = __expf(2.f * xc);
    return (e - 1.f) / (e + 1.f);
}

// 16-block group barrier. R8: NO agent acquire/release (an agent acquire
// invalidates the whole XCD L2 -> 2.9 GB/step weight refetch, the R7 bottleneck).
// Protocol: __syncthreads drains vmcnt (L1 is write-through, so all stores are
// in L2); relaxed atomic counter (executes at device coherence point -> barrier
// itself is placement-independent); after the spin, invalidate L1 ONLY
// (buffer_inv sc0) so subsequent reads see the group's L2 data. Data path
// assumes group members share an XCD (mb in low blockIdx bits).
__device__ __forceinline__ void group_barrier(unsigned* cnt, unsigned target) {
    __syncthreads();   // compiler emits s_waitcnt vmcnt(0) before s_barrier
    if (threadIdx.x == 0) {
        __hip_atomic_fetch_add(cnt, 1u, __ATOMIC_RELAXED, __HIP_MEMORY_SCOPE_AGENT);
        while (__hip_atomic_load(cnt, __ATOMIC_RELAXED, __HIP_MEMORY_SCOPE_AGENT) < target)
            __builtin_amdgcn_s_sleep(2);
    }
    __syncthreads();
    // L1-only invalidate; L2 (holding weights + peer h-frags) stays intact.
    asm volatile("buffer_inv sc0\n\ts_waitcnt vmcnt(0)" ::: "memory");
}

// Fragment layout (verified R2+): element (row r, k) of a 16-row tile:
// lane = ((k%32)>>3)*16 + (r%16), slot = k%8; buffer [tile][ks][lane][slot] u16.
// C/D: col = lane&15, row = (lane>>4)*4 + reg.

#define MLOADA(Ad, ksv) do { const unsigned ko = (unsigned)(ksv) * 512; \
  _Pragma("unroll") for (int m_ = 0; m_ < 2; m_++) { \
    Ad[m_*2+0] = *reinterpret_cast<const bf16x8*>(RAh + ao[m_] + ko); \
    Ad[m_*2+1] = *reinterpret_cast<const bf16x8*>(RAl + ao[m_] + ko); \
  } } while(0)
#define MLOADB(Bd, ksv) do { const unsigned ko = (unsigned)(ksv) * 512; \
  _Pragma("unroll") for (int i_ = 0; i_ < 6; i_++) { \
    Bd[i_*2+0] = *reinterpret_cast<const bf16x8*>(Bh + bo[i_] + ko); \
    Bd[i_*2+1] = *reinterpret_cast<const bf16x8*>(Bl + bo[i_] + ko); \
  } } while(0)
#define MMFMA(Av, Bv) do { \
  _Pragma("unroll") for (int m_ = 0; m_ < 2; m_++) \
  _Pragma("unroll") for (int i_ = 0; i_ < 6; i_++) \
    acc[m_][i_] = __builtin_amdgcn_mfma_f32_16x16x32_bf16(Av[m_*2+0], Bv[i_*2+0], acc[m_][i_], 0,0,0); \
  _Pragma("unroll") for (int m_ = 0; m_ < 2; m_++) \
  _Pragma("unroll") for (int i_ = 0; i_ < 6; i_++) \
    acc[m_][i_] = __builtin_amdgcn_mfma_f32_16x16x32_bf16(Av[m_*2+0], Bv[i_*2+1], acc[m_][i_], 0,0,0); \
  _Pragma("unroll") for (int m_ = 0; m_ < 2; m_++) \
  _Pragma("unroll") for (int i_ = 0; i_ < 6; i_++) \
    acc[m_][i_] = __builtin_amdgcn_mfma_f32_16x16x32_bf16(Av[m_*2+1], Bv[i_*2+0], acc[m_][i_], 0,0,0); \
  } while(0)

#define HLOADA(Ad, ksv) do { const unsigned ko = (unsigned)(ksv) * 512; \
  _Pragma("unroll") for (int m_ = 0; m_ < 2; m_++) { \
    Ad[m_*2+0] = *reinterpret_cast<const bf16x8*>(WAh + ao[m_] + ko); \
    Ad[m_*2+1] = *reinterpret_cast<const bf16x8*>(WAl + ao[m_] + ko); \
  } } while(0)
#define HLOADB(Bd, ksv) do { const unsigned ko = (unsigned)(ksv) * 512; \
  _Pragma("unroll") for (int n_ = 0; n_ < 2; n_++) { \
    Bd[n_*2+0] = *reinterpret_cast<const bf16x8*>(W1H + bo1[n_] + ko); \
    Bd[n_*2+1] = *reinterpret_cast<const bf16x8*>(W1L + bo1[n_] + ko); \
  } } while(0)
#define HMFMA(Av, Bv) do { \
  _Pragma("unroll") for (int m_ = 0; m_ < 2; m_++) \
  _Pragma("unroll") for (int n_ = 0; n_ < 2; n_++) { \
    hacc[m_][n_] = __builtin_amdgcn_mfma_f32_16x16x32_bf16(Av[m_*2+0], Bv[n_*2+0], hacc[m_][n_], 0,0,0); \
    hacc[m_][n_] = __builtin_amdgcn_mfma_f32_16x16x32_bf16(Av[m_*2+0], Bv[n_*2+1], hacc[m_][n_], 0,0,0); \
    hacc[m_][n_] = __builtin_amdgcn_mfma_f32_16x16x32_bf16(Av[m_*2+1], Bv[n_*2+0], hacc[m_][n_], 0,0,0); \
  } } while(0)

// ================= persistent kernel: all 72 steps, 2 blocks/CU =================
__global__ __launch_bounds__(256, 2) void main_kernel(
    ushortt* Ah0, ushortt* Al0, ushortt* Ah1, ushortt* Al1,
    const ushortt* __restrict__ WheH, const ushortt* __restrict__ WheL,
    const ushortt* __restrict__ WhdH, const ushortt* __restrict__ WhdL,
    const ushortt* __restrict__ W1H,  const ushortt* __restrict__ W1L,
    const float* __restrict__ Ue, const float* __restrict__ ce,
    const float* __restrict__ Ud, const float* __restrict__ cd,
    const float* __restrict__ bhe, const float* __restrict__ bhd,
    const float* __restrict__ traj, const float* __restrict__ ctx,
    const float* __restrict__ b1v, const float* __restrict__ W2,
    const float* __restrict__ b2v, float* __restrict__ dpart,
    unsigned* bar, float* __restrict__ out)
{
    __shared__ float hbuf[128 * 36];     // epilogue repack staging
    __shared__ float sstate[128 * 2];    // decoder state (redundant per group)
    const int mb = blockIdx.x & 31;      // LOW bits -> XCD = mb%8; group = same mb
    const int jb = blockIdx.x >> 5;      // 0..15
    const int w = threadIdx.x >> 6, lane = threadIdx.x & 63;
    const int quad = lane >> 4, l15 = lane & 15;
    const int mtg = mb * 8 + w * 2;      // wave's 2 global m-tiles
    const int jlo = jb * 32;
    unsigned* grpcnt = bar + mb * 16;    // padded counter per group
    unsigned tgt = 0;

    ushortt* bh_[2] = {Ah0, Ah1};
    ushortt* bl_[2] = {Al0, Al1};

    unsigned ao[2], bo[6], bo1[2];
#pragma unroll
    for (int mt = 0; mt < 2; mt++) ao[mt] = (unsigned)(mtg + mt) * TILE_U16 + lane * 8;
#pragma unroll
    for (int g = 0; g < 3; g++)
#pragma unroll
        for (int jt = 0; jt < 2; jt++)
            bo[g*2+jt] = (unsigned)(g*32 + jb*2 + jt) * TILE_U16 + lane * 8;
#pragma unroll
    for (int nt = 0; nt < 2; nt++) bo1[nt] = (unsigned)(jb*2 + nt) * TILE_U16 + lane * 8;

    // head constants (fixed all steps)
    float b1r[2], w2a[2], w2b[2];
#pragma unroll
    for (int nt = 0; nt < 2; nt++) {
        int col = jlo + nt*16 + l15;
        b1r[nt] = b1v[col]; w2a[nt] = W2[col]; w2b[nt] = W2[HH + col];
    }
    const float b20 = b2v[0], b21 = b2v[1];

    // per-phase GRU epilogue constants
    float Ur0[2],Ur1[2],Uz0[2],Uz1[2],Un0[2],Un1[2],Crr[2],Czz[2],bhn[2],cinn[2];

#pragma unroll 1
    for (int s = 0; s < TT + HOR; s++) {
        const bool enc = s < TT;
        if (s == 0 || s == TT) {
            const float* U  = enc ? Ue : Ud;
            const float* ci = enc ? ce : cd;
            const float* bh = enc ? bhe : bhd;
#pragma unroll
            for (int jt = 0; jt < 2; jt++) {
                int j = jlo + jt*16 + l15;
                Ur0[jt] = U[j*2];            Ur1[jt] = U[j*2+1];
                Uz0[jt] = U[(512+j)*2];      Uz1[jt] = U[(512+j)*2+1];
                Un0[jt] = U[(1024+j)*2];     Un1[jt] = U[(1024+j)*2+1];
                Crr[jt] = ci[j] + bh[j];
                Czz[jt] = ci[512+j] + bh[512+j];
                cinn[jt] = ci[1024+j];       bhn[jt] = bh[1024+j];
            }
            if (!enc) {
                if (threadIdx.x < 128) {
                    int lrow = threadIdx.x;
                    const float* sp = traj + (((size_t)mb * TT + 23) * OO + lrow) * 2;
                    sstate[lrow*2] = sp[0]; sstate[lrow*2+1] = sp[1];
                }
                __syncthreads();
            }
        }
        const ushortt* RAh = bh_[s & 1];
        const ushortt* RAl = bl_[s & 1];
        ushortt* WAh = bh_[(s + 1) & 1];
        ushortt* WAl = bl_[(s + 1) & 1];
        const ushortt* Bh = enc ? WheH : WhdH;
        const ushortt* Bl = enc ? WheL : WhdL;

        f32x4 acc[2][6];
#pragma unroll
        for (int a = 0; a < 2; a++)
#pragma unroll
            for (int b = 0; b < 6; b++) acc[a][b] = (f32x4){0.f,0.f,0.f,0.f};

        if (s > 0) {
            bf16x8 aC[4], bC[12], aN[4], bN[12];
            MLOADA(aC, 0); MLOADB(bC, 0);
#pragma unroll 1
            for (int ks = 0; ks < 14; ks += 2) {
                MLOADA(aN, ks+1); MLOADB(bN, ks+1);
                MMFMA(aC, bC);
                MLOADA(aC, ks+2); MLOADB(bC, ks+2);
                MMFMA(aN, bN);
            }
            MLOADA(aN, 15); MLOADB(bN, 15);
            MMFMA(aC, bC);   // ks = 14
            MMFMA(aN, bN);   // ks = 15
        }

        // ---- x values per (mt, reg) row ----
        float x0v[2][4], x1v[2][4];
#pragma unroll
        for (int mt = 0; mt < 2; mt++)
#pragma unroll
            for (int reg = 0; reg < 4; reg++) {
                int lrow = (w*2 + mt) * 16 + quad * 4 + reg;
                if (enc) {
                    const float* p = traj + (((size_t)mb * TT + s) * OO + lrow) * 2;
                    x0v[mt][reg] = p[0]; x1v[mt][reg] = p[1];
                } else {
                    x0v[mt][reg] = sstate[lrow*2]; x1v[mt][reg] = sstate[lrow*2+1];
                }
            }

        // ---- GRU epilogue ----
#pragma unroll
        for (int mt = 0; mt < 2; mt++)
#pragma unroll
            for (int jt = 0; jt < 2; jt++) {
                int qk = jt*2 + (l15 >> 3), slot = l15 & 7;
#pragma unroll
                for (int reg = 0; reg < 4; reg++) {
                    float x0 = x0v[mt][reg], x1 = x1v[mt][reg];
                    float pr = acc[mt][0+jt][reg] + fmaf(x1, Ur1[jt], fmaf(x0, Ur0[jt], Crr[jt]));
                    float pz = acc[mt][2+jt][reg] + fmaf(x1, Uz1[jt], fmaf(x0, Uz0[jt], Czz[jt]));
                    float hn = acc[mt][4+jt][reg] + bhn[jt];
                    float inn = fmaf(x1, Un1[jt], fmaf(x0, Un0[jt], cinn[jt]));
                    float hold = 0.f;
                    if (s > 0) {
                        unsigned pos = (unsigned)(mtg + mt) * TILE_U16 + (unsigned)jb * 512
                                     + (unsigned)(qk*16 + quad*4 + reg) * 8 + slot;
                        hold = bf2f(RAh[pos]) + bf2f(RAl[pos]);
                    }
                    float rg = sigm(pr), zg = sigm(pz);
                    float nn = tanh_fast(inn + rg * hn);
                    float h = (1.f - zg) * nn + zg * hold;
                    if (enc && s == TT - 1)
                        h += ctx[(size_t)mb * HH + jlo + jt*16 + l15];
                    hbuf[(w*32 + mt*16 + quad*4 + reg) * 36 + jt*16 + l15] = h;
                }
            }
        __syncthreads();
        // repack LDS tile -> A-frags slice ks == jb of write buffer
#pragma unroll
        for (int rr = 0; rr < 2; rr++) {
            int fr = threadIdx.x + 256 * rr;       // 0..511
            int mt8 = fr >> 6, fl = fr & 63;
            int qk = fl >> 4, rloc = mt8 * 16 + (fl & 15);
            const float4 v0 = *reinterpret_cast<const float4*>(&hbuf[rloc * 36 + qk * 8]);
            const float4 v1 = *reinterpret_cast<const float4*>(&hbuf[rloc * 36 + qk * 8 + 4]);
            float src[8] = {v0.x, v0.y, v0.z, v0.w, v1.x, v1.y, v1.z, v1.w};
            bf16x8 hv, lv;
#pragma unroll
            for (int q = 0; q < 8; q++) {
                ushortt hi, lo; splitbf(src[q], hi, lo);
                hv[q] = (short)hi; lv[q] = (short)lo;
            }
            unsigned base = (unsigned)(mb*8 + mt8) * TILE_U16 + (unsigned)jb * 512 + fl * 8;
            *reinterpret_cast<bf16x8*>(WAh + base) = hv;
            *reinterpret_cast<bf16x8*>(WAl + base) = lv;
        }
        __syncthreads();   // hbuf reuse safety (next iteration writes hbuf)

        // B1: h_{s+1} frags complete for this group
        tgt += 16;
        group_barrier(grpcnt, tgt);

        if (!enc) {
            // ---- head: this block does W1 cols [jb*32, jb*32+32) for its 128 rows ----
            f32x4 hacc[2][2];
#pragma unroll
            for (int a = 0; a < 2; a++)
#pragma unroll
                for (int b = 0; b < 2; b++) hacc[a][b] = (f32x4){0.f,0.f,0.f,0.f};
            {
                bf16x8 aC[4], bC[4], aN[4], bN[4];
                HLOADA(aC, 0); HLOADB(bC, 0);
#pragma unroll 1
                for (int ks = 0; ks < 14; ks += 2) {
                    HLOADA(aN, ks+1); HLOADB(bN, ks+1);
                    HMFMA(aC, bC);
                    HLOADA(aC, ks+2); HLOADB(bC, ks+2);
                    HMFMA(aN, bN);
                }
                HLOADA(aN, 15); HLOADB(bN, 15);
                HMFMA(aC, bC);
                HMFMA(aN, bN);
            }
            float p0[2][4], p1[2][4];
#pragma unroll
            for (int mt = 0; mt < 2; mt++)
#pragma unroll
                for (int reg = 0; reg < 4; reg++) { p0[mt][reg] = 0.f; p1[mt][reg] = 0.f; }
#pragma unroll
            for (int mt = 0; mt < 2; mt++)
#pragma unroll
                for (int nt = 0; nt < 2; nt++)
#pragma unroll
                    for (int reg = 0; reg < 4; reg++) {
                        float v = hacc[mt][nt][reg] + b1r[nt];
                        v = 0.5f * v * (1.0f + erff(v * 0.70710678118654752440f));
                        p0[mt][reg] = fmaf(v, w2a[nt], p0[mt][reg]);
                        p1[mt][reg] = fmaf(v, w2b[nt], p1[mt][reg]);
                    }
#pragma unroll
            for (int m = 1; m < 16; m <<= 1)
#pragma unroll
                for (int mt = 0; mt < 2; mt++)
#pragma unroll
                    for (int reg = 0; reg < 4; reg++) {
                        p0[mt][reg] += __shfl_xor(p0[mt][reg], m, 64);
                        p1[mt][reg] += __shfl_xor(p1[mt][reg], m, 64);
                    }
            if (l15 == 0) {
#pragma unroll
                for (int mt = 0; mt < 2; mt++)
#pragma unroll
                    for (int reg = 0; reg < 4; reg++) {
                        int lrow = (w*2 + mt) * 16 + quad * 4 + reg;
                        float* dp = dpart + ((size_t)(mb*16 + jb) * 128 + lrow) * 2;
                        dp[0] = p0[mt][reg]; dp[1] = p1[mt][reg];
                    }
            }
            // B2: all partials visible
            tgt += 16;
            group_barrier(grpcnt, tgt);
            // ---- finalize: reduce partials, update state (LDS), write out ----
            if (threadIdx.x < 128) {
                int lrow = threadIdx.x;
                float d0 = 0.f, d1 = 0.f;
#pragma unroll
                for (int j2 = 0; j2 < 16; j2++) {
                    const float* dp = dpart + ((size_t)(mb*16 + j2) * 128 + lrow) * 2;
                    d0 += dp[0]; d1 += dp[1];
                }
                d0 += b20; d1 += b21;
                d0 = 2.0f * tanhf(d0 * 0.5f);
                d1 = 2.0f * tanhf(d1 * 0.5f);
                float s0 = sstate[lrow*2] + d0;
                s0 = fminf(fmaxf(s0, -90.f), 90.f);
                float s1 = sstate[lrow*2+1] + d1;
                float rrm = fmodf(s1, 360.f);
                if (rrm < 0.f) rrm += 360.f;
                sstate[lrow*2] = s0; sstate[lrow*2+1] = rrm;
                if (jb == 0) {
                    float* op = out + (((size_t)mb * HOR + (s - TT)) * OO + lrow) * 2;
                    op[0] = s0; op[1] = rrm;
                }
            }
            __syncthreads();   // sstate ready for next step's epilogue
        }
    }
}

// ================= single prep kernel: packs + fuse + ctx + barrier zero =================
__device__ __forceinline__ void pack16(const float* __restrict__ W,
                                       ushortt* __restrict__ Fh, ushortt* __restrict__ Fl,
                                       int item) {
    int n = item >> 6, rem = item & 63;
    int ks = rem >> 2, quadk = rem & 3;
    int nt = n >> 4, l15 = n & 15;
    ushortt hv[8], lv[8];
#pragma unroll
    for (int q = 0; q < 8; q++) {
        float v = W[(size_t)n * 512 + ks*32 + quadk*8 + q];
        ushortt hi, lo; splitbf(v, hi, lo);
        hv[q] = hi; lv[q] = lo;
    }
    size_t pos = ((size_t)nt * TILE_U16) + (size_t)ks * 512 + (quadk*16 + l15) * 8;
#pragma unroll
    for (int q = 0; q < 8; q++) { Fh[pos + q] = hv[q]; Fl[pos + q] = lv[q]; }
}

__global__ __launch_bounds__(256) void prep_kernel(
    const float* __restrict__ Wh_enc, const float* __restrict__ Wh_cell,
    const float* __restrict__ W1,
    const float* __restrict__ Wi_enc, const float* __restrict__ bi_enc,
    const float* __restrict__ Wi_cell, const float* __restrict__ bi_cell,
    const float* __restrict__ W_emb, const float* __restrict__ b_emb,
    const float* __restrict__ z, const float* __restrict__ Wc, const float* __restrict__ bc,
    ushortt* __restrict__ WheH, ushortt* __restrict__ WheL,
    ushortt* __restrict__ WhdH, ushortt* __restrict__ WhdL,
    ushortt* __restrict__ W1H, ushortt* __restrict__ W1L,
    float* __restrict__ Ue, float* __restrict__ ce,
    float* __restrict__ Ud, float* __restrict__ cd,
    float* __restrict__ ctx, unsigned* __restrict__ bar)
{
    int b = blockIdx.x;
    if (b < 384) {
        pack16(Wh_enc, WheH, WheL, b * 256 + threadIdx.x);
    } else if (b < 768) {
        pack16(Wh_cell, WhdH, WhdL, (b - 384) * 256 + threadIdx.x);
    } else if (b < 896) {
        pack16(W1, W1H, W1L, (b - 768) * 256 + threadIdx.x);
    } else if (b < 1664) {
        // fuse: wave per output j (U = Wi*W_emb, c = Wi*b_emb + bi)
        int w = threadIdx.x >> 6, lane = threadIdx.x & 63;
        int gidx = (b - 896) * 4 + w;           // 0..3071
        int which = gidx >= G3;
        int j = gidx - which * G3;
        const float* Wi = which ? Wi_cell : Wi_enc;
        const float* bi = which ? bi_cell : bi_enc;
        float u0 = 0.f, u1 = 0.f, cc = 0.f;
#pragma unroll
        for (int i = 0; i < 8; i++) {
            int k = i * 64 + lane;
            float wv = Wi[(size_t)j * HH + k];
            u0 = fmaf(wv, W_emb[2*k],   u0);
            u1 = fmaf(wv, W_emb[2*k+1], u1);
            cc = fmaf(wv, b_emb[k],     cc);
        }
#pragma unroll
        for (int m = 1; m < 64; m <<= 1) {
            u0 += __shfl_xor(u0, m, 64);
            u1 += __shfl_xor(u1, m, 64);
            cc += __shfl_xor(cc, m, 64);
        }
        if (lane == 0) {
            float* Uo = which ? Ud : Ue;
            float* cv = which ? cd : ce;
            Uo[j*2] = u0; Uo[j*2+1] = u1; cv[j] = cc + bi[j];
        }
    } else if (b < 1728) {
        // ctx = z @ Wc^T + bc   (32 x 512)
        int idx = (b - 1664) * 256 + threadIdx.x;
        int bb = idx >> 9, j = idx & 511;
        float acc = bc[j];
        const float4* zp = (const float4*)(z + (size_t)bb * CTXD);
        const float4* wp = (const float4*)(Wc + (size_t)j * CTXD);
#pragma unroll 4
        for (int k = 0; k < CTXD / 4; k++) {
            float4 a = zp[k], ww = wp[k];
            acc = fmaf(a.x, ww.x, fmaf(a.y, ww.y, fmaf(a.z, ww.z, fmaf(a.w, ww.w, acc))));
        }
        ctx[idx] = acc;
    } else {
        bar[threadIdx.x] = 0u;
        bar[threadIdx.x + 256] = 0u;
    }
}

extern "C" void kernel_launch(void* const* d_in, const int* in_sizes, int n_in,
                              void* d_out, int out_size, void* d_ws, size_t ws_size,
                              hipStream_t stream) {
    const float* z_ctx   = (const float*)d_in[0];
    const float* traj    = (const float*)d_in[1];
    const float* W_emb   = (const float*)d_in[2];
    const float* b_emb   = (const float*)d_in[3];
    const float* W_ctx   = (const float*)d_in[4];
    const float* b_ctx   = (const float*)d_in[5];
    const float* Wi_enc  = (const float*)d_in[6];
    const float* Wh_enc  = (const float*)d_in[7];
    const float* bi_enc  = (const float*)d_in[8];
    const float* bh_enc  = (const float*)d_in[9];
    const float* Wi_cell = (const float*)d_in[10];
    const float* Wh_cell = (const float*)d_in[11];
    const float* bi_cell = (const float*)d_in[12];
    const float* bh_cell = (const float*)d_in[13];
    const float* W1      = (const float*)d_in[14];
    const float* b1      = (const float*)d_in[15];
    const float* W2      = (const float*)d_in[16];
    const float* b2      = (const float*)d_in[17];
    float* out = (float*)d_out;

    char* ws = (char*)d_ws;
    size_t off = 0;
    auto alloc = [&](size_t bytes) { void* p = ws + off; off += (bytes + 255) & ~(size_t)255; return p; };
    const size_t hfrag  = (size_t)256 * TILE_U16 * 2;   // 4 MB per h buffer
    const size_t wfrag  = (size_t)96  * TILE_U16 * 2;   // Wh (96 tiles)
    const size_t w1frag = (size_t)32  * TILE_U16 * 2;   // W1 (32 tiles)
    ushortt* Ah0 = (ushortt*)alloc(hfrag);
    ushortt* Al0 = (ushortt*)alloc(hfrag);
    ushortt* Ah1 = (ushortt*)alloc(hfrag);
    ushortt* Al1 = (ushortt*)alloc(hfrag);
    ushortt* WheH = (ushortt*)alloc(wfrag);
    ushortt* WheL = (ushortt*)alloc(wfrag);
    ushortt* WhdH = (ushortt*)alloc(wfrag);
    ushortt* WhdL = (ushortt*)alloc(wfrag);
    ushortt* W1H  = (ushortt*)alloc(w1frag);
    ushortt* W1L  = (ushortt*)alloc(w1frag);
    float*   Ue   = (float*)alloc((size_t)G3 * 2 * 4);
    float*   ce   = (float*)alloc((size_t)G3 * 4);
    float*   Ud   = (float*)alloc((size_t)G3 * 2 * 4);
    float*   cd   = (float*)alloc((size_t)G3 * 4);
    float*   ctxb = (float*)alloc((size_t)BB * HH * 4);
    float*   dpart = (float*)alloc((size_t)32 * 16 * 128 * 2 * 4);  // 512 KB
    unsigned* bar  = (unsigned*)alloc(512 * 4);

    prep_kernel<<<1729, 256, 0, stream>>>(Wh_enc, Wh_cell, W1,
                                          Wi_enc, bi_enc, Wi_cell, bi_cell,
                                          W_emb, b_emb, z_ctx, W_ctx, b_ctx,
                                          WheH, WheL, WhdH, WhdL, W1H, W1L,
                                          Ue, ce, Ud, cd, ctxb, bar);

    main_kernel<<<512, 256, 0, stream>>>(Ah0, Al0, Ah1, Al1,
                                         WheH, WheL, WhdH, WhdL, W1H, W1L,
                                         Ue, ce, Ud, cd, bh_enc, bh_cell,
                                         traj, ctxb, b1, W2, b2,
                                         dpart, bar, out);
}